// Round 5
// baseline (219.126 us; speedup 1.0000x reference)
//
#include <hip/hip_runtime.h>
#include <math.h>

#define W3 96
#define HW 9216        // 96*96
#define DHW 884736     // 96^3
#define NB 2
#define BIGL (1<<30)
#define INF10 1.0e10f

// accumulator area (4B words) at ws offset 0
#define A_ROOTCNT 0    // 2 ints
#define A_ROOTS   2    // 2*8 ints
#define A_SUMS    28   // 2*12 floats: [accA(4), accM(4), cnt(4)] per b
#define A_TOTAL   64

__global__ void k_init(const int* __restrict__ y, int* __restrict__ lab,
                       int* __restrict__ acc) {
    int i = blockIdx.x * blockDim.x + threadIdx.x;
    if (blockIdx.x == 0 && threadIdx.x < A_TOTAL) acc[threadIdx.x] = 0;
    if (i >= NB * DHW) return;
    int v = i % DHW;
    lab[i] = (y[i] > 0) ? v : BIGL;
}

// chase to root. Plain loads may be stale (older, >= current) values: any
// stale value is a valid former ancestor; labels only decrease, so the chain
// strictly descends and terminates. Authoritative checks happen via atomicMin.
__device__ __forceinline__ int ufind(int* __restrict__ lb, int v) {
    int p = lb[v];
    while (true) { int pp = lb[p]; if (pp == p) break; p = pp; }
    return p;
}

// lock-free union (Playne-Yock): link larger root under smaller via atomicMin,
// retry with the displaced value on contention. Max index strictly decreases
// per retry -> terminates. Final forest: one tree per component, root = min
// raster index (matches the reference's converged min-label propagation).
__device__ void unite(int* __restrict__ lb, int a, int b) {
    while (true) {
        a = ufind(lb, a); b = ufind(lb, b);
        if (a == b) return;
        int mn = min(a, b), mx = max(a, b);
        int old = atomicMin(&lb[mx], mn);
        if (old == mx) return;
        a = old; b = mn;
    }
}

// one pass over the 13 backward-neighbor edges of each masked voxel
__global__ void k_merge(const int* __restrict__ y, int* __restrict__ lab) {
    int i = blockIdx.x * blockDim.x + threadIdx.x;
    if (i >= NB * DHW) return;
    if (y[i] <= 0) return;                 // ~98% of threads exit here
    int b = i / DHW, v = i - b * DHW;
    int d = v / HW; int rem = v - d * HW; int h = rem / W3; int w = rem - h * W3;
    const int* yb = y + b * DHW;
    int* lb = lab + b * DHW;
    const int offs[13][3] = {
        {-1,-1,-1},{-1,-1,0},{-1,-1,1},
        {-1, 0,-1},{-1, 0,0},{-1, 0,1},
        {-1, 1,-1},{-1, 1,0},{-1, 1,1},
        { 0,-1,-1},{ 0,-1,0},{ 0,-1,1},
        { 0, 0,-1}};
    #pragma unroll
    for (int k = 0; k < 13; k++) {
        int dd = d + offs[k][0], hh = h + offs[k][1], ww = w + offs[k][2];
        if ((unsigned)dd >= W3 || (unsigned)hh >= W3 || (unsigned)ww >= W3) continue;
        int u = dd * HW + hh * W3 + ww;
        if (yb[u] > 0) unite(lb, v, u);
    }
}

// flatten to roots + collect them
__global__ void k_compress(int* __restrict__ lab, int* __restrict__ acc) {
    int i = blockIdx.x * blockDim.x + threadIdx.x;
    if (i >= NB * DHW) return;
    int b = i / DHW, v = i - b * DHW;
    int* lb = lab + b * DHW;
    int p = lb[v];
    if (p == BIGL) return;
    while (true) { int pp = lb[p]; if (pp == p) break; p = pp; }
    lb[v] = p;
    if (p == v) {
        int c = atomicAdd(&acc[A_ROOTCNT + b], 1);
        if (c < 8) acc[A_ROOTS + b * 8 + c] = v;
    }
}

// rank of label t among component roots (1..K), 0 for background.
// rank over the UNSORTED roots list == searchsorted over sorted uniq.
__device__ __forceinline__ int rankc(int t, const int rt[8], int n) {
    if (t == BIGL) return 0;
    int c = 1;
    #pragma unroll
    for (int p = 0; p < 8; p++) c += (p < n && rt[p] < t) ? 1 : 0;
    return c;
}

// shared EDT tile compute: 8 rows x 96 in lds[8][100]; thread t handles
// row j=t>>5, outputs p = (t&31) + 32k, k<3. Keys are dist2 + label/8 (exact).
__device__ __forceinline__ void edt_compute(const float (*lds)[100], int t,
                                            float best[3]) {
    int j = t >> 5, p0 = t & 31;
    float dq0 = (float)p0, dq1 = (float)(p0 + 32), dq2 = (float)(p0 + 64);
    best[0] = best[1] = best[2] = 3.9e37f;
    for (int q4 = 0; q4 < 24; q4++) {
        float4 v4 = *(const float4*)&lds[j][q4 * 4];
        #pragma unroll
        for (int s = 0; s < 4; s++) {
            float val = (&v4.x)[s];
            best[0] = fminf(best[0], fmaf(dq0, dq0, val));
            best[1] = fminf(best[1], fmaf(dq1, dq1, val));
            best[2] = fminf(best[2], fmaf(dq2, dq2, val));
            dq0 -= 1.0f; dq1 -= 1.0f; dq2 -= 1.0f;
        }
    }
}

// pass along D: reads lab (+roots -> rank), writes keys to out
__global__ void k_pedtD(const int* __restrict__ lab, const int* __restrict__ acc,
                        float* __restrict__ out) {
    __shared__ float lds[8][100];
    int blk = blockIdx.x;
    int b = blk / 1152, rem0 = (blk % 1152) * 8;
    const int* lp = lab + b * DHW + rem0;
    float* op = out + b * DHW + rem0;
    int t = threadIdx.x;
    int n = acc[A_ROOTCNT + b]; if (n > 8) n = 8;
    int rt[8];
    #pragma unroll
    for (int p = 0; p < 8; p++) rt[p] = acc[A_ROOTS + b * 8 + p];
    #pragma unroll
    for (int m = 0; m < 3; m++) {
        int e = t + 256 * m;
        int q = e >> 3, j = e & 7;
        int c = rankc(lp[q * HW + j], rt, n);
        lds[j][q] = (c > 0) ? (float)c * 0.125f : INF10;
    }
    __syncthreads();
    float best[3];
    edt_compute(lds, t, best);
    __syncthreads();
    int j = t >> 5, p0 = t & 31;
    lds[j][p0] = best[0]; lds[j][p0 + 32] = best[1]; lds[j][p0 + 64] = best[2];
    __syncthreads();
    #pragma unroll
    for (int m = 0; m < 3; m++) {
        int e = t + 256 * m;
        op[(e >> 3) * HW + (e & 7)] = lds[e & 7][e >> 3];
    }
}

// pass along H: keys -> keys
__global__ void k_pedtH(const float* __restrict__ fin, float* __restrict__ out) {
    __shared__ float lds[8][100];
    int blk = blockIdx.x;
    int b = blk / 1152, r = blk % 1152;
    int d = r / 12, w0 = (r % 12) * 8;
    size_t base = (size_t)b * DHW + d * HW + w0;
    const float* fp = fin + base;
    float* op = out + base;
    int t = threadIdx.x;
    #pragma unroll
    for (int m = 0; m < 3; m++) {
        int e = t + 256 * m;
        lds[e & 7][e >> 3] = fp[(e >> 3) * W3 + (e & 7)];
    }
    __syncthreads();
    float best[3];
    edt_compute(lds, t, best);
    __syncthreads();
    int j = t >> 5, p0 = t & 31;
    lds[j][p0] = best[0]; lds[j][p0 + 32] = best[1]; lds[j][p0 + 64] = best[2];
    __syncthreads();
    #pragma unroll
    for (int m = 0; m < 3; m++) {
        int e = t + 256 * m;
        op[(e >> 3) * W3 + (e & 7)] = lds[e & 7][e >> 3];
    }
}

__device__ __forceinline__ float wred(float v) {
    v += __shfl_xor(v, 32, 64);
    v += __shfl_xor(v, 16, 64);
    v += __shfl_xor(v, 8, 64);
    v += __shfl_xor(v, 4, 64);
    v += __shfl_xor(v, 2, 64);
    v += __shfl_xor(v, 1, 64);
    return v;
}

// pass along W fused with dice accumulation
__global__ void k_pedtW_acc(const float* __restrict__ fin,
                            const float* __restrict__ x,
                            const int* __restrict__ lab,
                            int* __restrict__ acc) {
    __shared__ float lds[8][100];
    __shared__ float red[4][12];
    int blk = blockIdx.x;
    int b = blk / 1152, dh0 = (blk % 1152) * 8;
    size_t base = (size_t)b * DHW + (size_t)dh0 * W3;
    int t = threadIdx.x;
    int n = acc[A_ROOTCNT + b]; if (n > 8) n = 8;
    int rt[8];
    #pragma unroll
    for (int p = 0; p < 8; p++) rt[p] = acc[A_ROOTS + b * 8 + p];
    #pragma unroll
    for (int m = 0; m < 3; m++) {
        int e = t + 256 * m;
        int j2 = e / 96, q2 = e - j2 * 96;
        lds[j2][q2] = fin[base + e];
    }
    __syncthreads();
    float best[3];
    edt_compute(lds, t, best);

    int j = t >> 5, p0 = t & 31;
    float aA[4] = {0, 0, 0, 0}, aM[4] = {0, 0, 0, 0}, aC[4] = {0, 0, 0, 0};
    #pragma unroll
    for (int k = 0; k < 3; k++) {
        int p = p0 + 32 * k;
        size_t g = base + (size_t)j * W3 + p;
        int key8 = (int)(best[k] * 8.0f);
        int seg = (key8 & 7) - 1;
        seg = (seg < 0) ? 0 : ((seg > 3) ? 3 : seg);
        float xs = 1.0f / (1.0f + expf(-x[g]));
        int c = rankc(lab[g], rt, n);
        #pragma unroll
        for (int s = 0; s < 4; s++) {
            aA[s] += (seg == s) ? xs : 0.0f;
            aM[s] += (c == s + 1) ? xs : 0.0f;
            aC[s] += (c == s + 1) ? 1.0f : 0.0f;
        }
    }
    #pragma unroll
    for (int s = 0; s < 4; s++) {
        aA[s] = wred(aA[s]); aM[s] = wred(aM[s]); aC[s] = wred(aC[s]);
    }
    int lane = t & 63, wv = t >> 6;
    if (lane == 0) {
        #pragma unroll
        for (int s = 0; s < 4; s++) {
            red[wv][s] = aA[s]; red[wv][4 + s] = aM[s]; red[wv][8 + s] = aC[s];
        }
    }
    __syncthreads();
    if (t < 12) {
        float v = red[0][t] + red[1][t] + red[2][t] + red[3][t];
        atomicAdd((float*)&acc[A_SUMS + b * 12 + t], v);
    }
}

__global__ void k_loss(const int* __restrict__ acc, float* __restrict__ out) {
    if (threadIdx.x == 0 && blockIdx.x == 0) {
        const float* sums = (const float*)&acc[A_SUMS];
        float total = 0.0f;
        for (int b = 0; b < NB; b++) {
            int n = acc[A_ROOTCNT + b];
            int K = (n > 5) ? 5 : n;
            float s = 0.0f;
            for (int r = 0; r < 4; r++) {
                if (r < K) {
                    float A = sums[b * 12 + r];        // sum xs by voronoi seg
                    float M = sums[b * 12 + 4 + r];    // sum xs over comp r+1
                    float C = sums[b * 12 + 8 + r];    // count comp r+1
                    float inter = (float)(r + 1) * M;
                    float sy = (float)(r + 1) * C;
                    s += 2.0f * inter / (A + sy);
                }
            }
            float Kf = (float)(K > 0 ? K : 1);
            total += (K == 0) ? 1.0f : (1.0f - s / Kf);
        }
        out[0] = total / (float)NB;
    }
}

extern "C" void kernel_launch(void* const* d_in, const int* in_sizes, int n_in,
                              void* d_out, int out_size, void* d_ws, size_t ws_size,
                              hipStream_t stream) {
    const float* x = (const float*)d_in[0];
    const int*   y = (const int*)d_in[1];
    float* out = (float*)d_out;

    char* ws = (char*)d_ws;
    int*   acc = (int*)ws;
    int*   lab = (int*)(ws + 1024);
    float* kA  = (float*)(ws + 1024 + (size_t)NB * DHW * 4);
    float* kB  = (float*)((char*)kA + (size_t)NB * DHW * 4);

    dim3 blk(256);
    dim3 g1((NB * DHW) / 256);   // 6912, exact
    dim3 g2(NB * 1152);          // 2304 tiles per pass

    k_init<<<g1, blk, 0, stream>>>(y, lab, acc);
    k_merge<<<g1, blk, 0, stream>>>(y, lab);
    k_compress<<<g1, blk, 0, stream>>>(lab, acc);
    k_pedtD<<<g2, blk, 0, stream>>>(lab, acc, kA);
    k_pedtH<<<g2, blk, 0, stream>>>(kA, kB);
    k_pedtW_acc<<<g2, blk, 0, stream>>>(kB, x, lab, acc);
    k_loss<<<1, 64, 0, stream>>>(acc, out);
}

// Round 6
// 215.692 us; speedup vs baseline: 1.0159x; 1.0159x over previous
//
#include <hip/hip_runtime.h>
#include <math.h>

#define W3 96
#define HW 9216        // 96*96
#define DHW 884736     // 96^3
#define NB 2
#define BIGL (1<<30)
#define INF10 1.0e10f

// accumulator area (4B words) at ws offset 0
#define A_ROOTCNT 0    // 2 ints
#define A_ROOTS   2    // 2*8 ints
#define A_SUMS    28   // 2*12 floats: [accA(4), accM(4), cnt(4)] per b
#define A_TOTAL   64

// ---------------- CCL: hierarchical union-find ----------------
// Tiles: 4(z) x 4(y) x 32(x); 24*24*3 = 1728 tiles/volume.
// Local e = dz*128 + dy*32 + dx.

__device__ __forceinline__ int findl(int* l, int v) {
    volatile int* vl = l;
    int p = vl[v];
    while (true) { int pp = vl[p]; if (pp == p) break; p = pp; }
    return p;
}

__device__ void unitel(int* l, int a, int b) {
    while (true) {
        a = findl(l, a); b = findl(l, b);
        if (a == b) return;
        int mn = min(a, b), mx = max(a, b);
        int old = atomicMin(&l[mx], mn);
        if (old == mx) return;
        a = old; b = mn;
    }
}

__constant__ int c_offs[13][3] = {
    {-1,-1,-1},{-1,-1,0},{-1,-1,1},
    {-1, 0,-1},{-1, 0,0},{-1, 0,1},
    {-1, 1,-1},{-1, 1,0},{-1, 1,1},
    { 0,-1,-1},{ 0,-1,0},{ 0,-1,1},
    { 0, 0,-1}};

// Phase A: per-tile union-find in LDS; write tile-root global index (or BIGL).
__global__ void k_local(const int* __restrict__ y, int* __restrict__ lab,
                        int* __restrict__ acc) {
    __shared__ int llab[512];
    int blk = blockIdx.x, t = threadIdx.x;
    if (blk == 0 && t < A_TOTAL) acc[t] = 0;
    int b = blk / 1728, tb = blk - b * 1728;
    int tz = tb / 72, rr = tb - tz * 72, ty = rr / 3, tx = rr - ty * 3;
    int d0 = tz * 4, h0 = ty * 4, w0 = tx * 32;
    const int* yb = y + b * DHW;
    int* lb = lab + b * DHW;

    int e0 = t, e1 = t + 256;
    int dz0 = e0 >> 7, dy0 = (e0 >> 5) & 3, dx0 = e0 & 31;
    int dz1 = e1 >> 7, dy1 = (e1 >> 5) & 3, dx1 = e1 & 31;
    int g0 = (d0 + dz0) * HW + (h0 + dy0) * W3 + (w0 + dx0);
    int g1 = (d0 + dz1) * HW + (h0 + dy1) * W3 + (w0 + dx1);
    int m0 = yb[g0] > 0, m1 = yb[g1] > 0;
    llab[e0] = m0 ? e0 : 0x7FFFFFFF;
    llab[e1] = m1 ? e1 : 0x7FFFFFFF;
    __syncthreads();

    volatile int* vl = llab;
    #pragma unroll
    for (int k = 0; k < 13; k++) {
        int oz = c_offs[k][0], oy = c_offs[k][1], ox = c_offs[k][2];
        if (m0) {
            int nz = dz0 + oz, ny = dy0 + oy, nx = dx0 + ox;
            if ((unsigned)nz < 4 && (unsigned)ny < 4 && (unsigned)nx < 32) {
                int ne = nz * 128 + ny * 32 + nx;
                if (vl[ne] < 512) unitel(llab, e0, ne);
            }
        }
        if (m1) {
            int nz = dz1 + oz, ny = dy1 + oy, nx = dx1 + ox;
            if ((unsigned)nz < 4 && (unsigned)ny < 4 && (unsigned)nx < 32) {
                int ne = nz * 128 + ny * 32 + nx;
                if (vl[ne] < 512) unitel(llab, e1, ne);
            }
        }
    }
    __syncthreads();

    if (m0) {
        int r = findl(llab, e0);
        lb[g0] = (d0 + (r >> 7)) * HW + (h0 + ((r >> 5) & 3)) * W3 + (w0 + (r & 31));
    } else lb[g0] = BIGL;
    if (m1) {
        int r = findl(llab, e1);
        lb[g1] = (d0 + (r >> 7)) * HW + (h0 + ((r >> 5) & 3)) * W3 + (w0 + (r & 31));
    } else lb[g1] = BIGL;
}

// global find/unite (Playne-Yock; monotone atomicMin, stale reads safe)
__device__ __forceinline__ int ufind(int* __restrict__ lb, int v) {
    int p = lb[v];
    while (true) { int pp = lb[p]; if (pp == p) break; p = pp; }
    return p;
}

__device__ void unite(int* __restrict__ lb, int a, int b) {
    while (true) {
        a = ufind(lb, a); b = ufind(lb, b);
        if (a == b) return;
        int mn = min(a, b), mx = max(a, b);
        int old = atomicMin(&lb[mx], mn);
        if (old == mx) return;
        a = old; b = mn;
    }
}

// Phase B: unite ONLY across tile boundaries (backward edges that leave the tile)
__global__ void k_bmerge(const int* __restrict__ y, int* __restrict__ lab) {
    int i = blockIdx.x * blockDim.x + threadIdx.x;
    if (i >= NB * DHW) return;
    if (y[i] <= 0) return;
    int b = i / DHW, v = i - b * DHW;
    int d = v / HW; int rem = v - d * HW; int h = rem / W3; int w = rem - h * W3;
    int fz = ((d & 3) == 0), fy = ((h & 3) == 0), fx = ((w & 31) == 0);
    if (!(fz | fy | fx)) return;          // interior of tile: fully handled locally
    const int* yb = y + b * DHW;
    int* lb = lab + b * DHW;
    #pragma unroll
    for (int k = 0; k < 13; k++) {
        int oz = c_offs[k][0], oy = c_offs[k][1], ox = c_offs[k][2];
        int cross = (fz && oz < 0) || (fy && oy < 0) || (fx && ox < 0);
        if (!cross) continue;
        int dd = d + oz, hh = h + oy, ww = w + ox;
        if ((unsigned)dd >= W3 || (unsigned)hh >= W3 || (unsigned)ww >= W3) continue;
        int u = dd * HW + hh * W3 + ww;
        if (yb[u] > 0) unite(lb, v, u);
    }
}

// Phase C: roots are exactly lab[v]==v; streaming collect (no rewrite pass)
__global__ void k_roots(const int* __restrict__ lab, int* __restrict__ acc) {
    int i = blockIdx.x * blockDim.x + threadIdx.x;
    if (i >= NB * DHW) return;
    int b = i / DHW, v = i - b * DHW;
    if (lab[i] == v) {
        int c = atomicAdd(&acc[A_ROOTCNT + b], 1);
        if (c < 8) acc[A_ROOTS + b * 8 + c] = v;
    }
}

// chase to root in the (now frozen) global forest
__device__ __forceinline__ int gfind(const int* __restrict__ lb, int t) {
    while (true) { int p = lb[t]; if (p == t) break; t = p; }
    return t;
}

// rank of ROOT t among component roots (1..K).
// rank over the UNSORTED roots list == searchsorted over sorted uniq.
__device__ __forceinline__ int rankc2(int t, const int rt[8], int n) {
    int c = 1;
    #pragma unroll
    for (int p = 0; p < 8; p++) c += (p < n && rt[p] < t) ? 1 : 0;
    return c;
}

// ---------------- packed-label EDT (key = dist2 + label/8, exact) ----------------

__device__ __forceinline__ void edt_compute(const float (*lds)[100], int t,
                                            float best[3]) {
    int j = t >> 5, p0 = t & 31;
    float dq0 = (float)p0, dq1 = (float)(p0 + 32), dq2 = (float)(p0 + 64);
    best[0] = best[1] = best[2] = 3.9e37f;
    for (int q4 = 0; q4 < 24; q4++) {
        float4 v4 = *(const float4*)&lds[j][q4 * 4];
        #pragma unroll
        for (int s = 0; s < 4; s++) {
            float val = (&v4.x)[s];
            best[0] = fminf(best[0], fmaf(dq0, dq0, val));
            best[1] = fminf(best[1], fmaf(dq1, dq1, val));
            best[2] = fminf(best[2], fmaf(dq2, dq2, val));
            dq0 -= 1.0f; dq1 -= 1.0f; dq2 -= 1.0f;
        }
    }
}

// pass along D: reads lab (find + rank -> key), writes keys
__global__ void k_pedtD(const int* __restrict__ lab, const int* __restrict__ acc,
                        float* __restrict__ out) {
    __shared__ float lds[8][100];
    int blk = blockIdx.x;
    int b = blk / 1152, rem0 = (blk % 1152) * 8;
    const int* lb = lab + b * DHW;
    const int* lp = lb + rem0;
    float* op = out + b * DHW + rem0;
    int t = threadIdx.x;
    int n = acc[A_ROOTCNT + b]; if (n > 8) n = 8;
    int rt[8];
    #pragma unroll
    for (int p = 0; p < 8; p++) rt[p] = acc[A_ROOTS + b * 8 + p];
    #pragma unroll
    for (int m = 0; m < 3; m++) {
        int e = t + 256 * m;
        int q = e >> 3, j = e & 7;
        int tv = lp[q * HW + j];
        float val = INF10;
        if (tv != BIGL) {
            int c = rankc2(gfind(lb, tv), rt, n);
            val = (float)c * 0.125f;
        }
        lds[j][q] = val;
    }
    __syncthreads();
    float best[3];
    edt_compute(lds, t, best);
    __syncthreads();
    int j = t >> 5, p0 = t & 31;
    lds[j][p0] = best[0]; lds[j][p0 + 32] = best[1]; lds[j][p0 + 64] = best[2];
    __syncthreads();
    #pragma unroll
    for (int m = 0; m < 3; m++) {
        int e = t + 256 * m;
        op[(e >> 3) * HW + (e & 7)] = lds[e & 7][e >> 3];
    }
}

// pass along H: keys -> keys
__global__ void k_pedtH(const float* __restrict__ fin, float* __restrict__ out) {
    __shared__ float lds[8][100];
    int blk = blockIdx.x;
    int b = blk / 1152, r = blk % 1152;
    int d = r / 12, w0 = (r % 12) * 8;
    size_t base = (size_t)b * DHW + d * HW + w0;
    const float* fp = fin + base;
    float* op = out + base;
    int t = threadIdx.x;
    #pragma unroll
    for (int m = 0; m < 3; m++) {
        int e = t + 256 * m;
        lds[e & 7][e >> 3] = fp[(e >> 3) * W3 + (e & 7)];
    }
    __syncthreads();
    float best[3];
    edt_compute(lds, t, best);
    __syncthreads();
    int j = t >> 5, p0 = t & 31;
    lds[j][p0] = best[0]; lds[j][p0 + 32] = best[1]; lds[j][p0 + 64] = best[2];
    __syncthreads();
    #pragma unroll
    for (int m = 0; m < 3; m++) {
        int e = t + 256 * m;
        op[(e >> 3) * W3 + (e & 7)] = lds[e & 7][e >> 3];
    }
}

__device__ __forceinline__ float wred(float v) {
    v += __shfl_xor(v, 32, 64);
    v += __shfl_xor(v, 16, 64);
    v += __shfl_xor(v, 8, 64);
    v += __shfl_xor(v, 4, 64);
    v += __shfl_xor(v, 2, 64);
    v += __shfl_xor(v, 1, 64);
    return v;
}

// pass along W fused with dice accumulation
__global__ void k_pedtW_acc(const float* __restrict__ fin,
                            const float* __restrict__ x,
                            const int* __restrict__ lab,
                            int* __restrict__ acc) {
    __shared__ float lds[8][100];
    __shared__ float red[4][12];
    int blk = blockIdx.x;
    int b = blk / 1152, dh0 = (blk % 1152) * 8;
    size_t base = (size_t)b * DHW + (size_t)dh0 * W3;
    const int* lb = lab + (size_t)b * DHW;
    int t = threadIdx.x;
    int n = acc[A_ROOTCNT + b]; if (n > 8) n = 8;
    int rt[8];
    #pragma unroll
    for (int p = 0; p < 8; p++) rt[p] = acc[A_ROOTS + b * 8 + p];
    #pragma unroll
    for (int m = 0; m < 3; m++) {
        int e = t + 256 * m;
        int j2 = e / 96, q2 = e - j2 * 96;
        lds[j2][q2] = fin[base + e];
    }
    __syncthreads();
    float best[3];
    edt_compute(lds, t, best);

    int j = t >> 5, p0 = t & 31;
    float aA[4] = {0, 0, 0, 0}, aM[4] = {0, 0, 0, 0}, aC[4] = {0, 0, 0, 0};
    #pragma unroll
    for (int k = 0; k < 3; k++) {
        int p = p0 + 32 * k;
        size_t g = base + (size_t)j * W3 + p;
        int key8 = (int)(best[k] * 8.0f);
        int seg = (key8 & 7) - 1;
        seg = (seg < 0) ? 0 : ((seg > 3) ? 3 : seg);
        float xs = 1.0f / (1.0f + expf(-x[g]));
        int tv = lab[g];
        int c = 0;
        if (tv != BIGL) c = rankc2(gfind(lb, tv), rt, n);
        #pragma unroll
        for (int s = 0; s < 4; s++) {
            aA[s] += (seg == s) ? xs : 0.0f;
            aM[s] += (c == s + 1) ? xs : 0.0f;
            aC[s] += (c == s + 1) ? 1.0f : 0.0f;
        }
    }
    #pragma unroll
    for (int s = 0; s < 4; s++) {
        aA[s] = wred(aA[s]); aM[s] = wred(aM[s]); aC[s] = wred(aC[s]);
    }
    int lane = t & 63, wv = t >> 6;
    if (lane == 0) {
        #pragma unroll
        for (int s = 0; s < 4; s++) {
            red[wv][s] = aA[s]; red[wv][4 + s] = aM[s]; red[wv][8 + s] = aC[s];
        }
    }
    __syncthreads();
    if (t < 12) {
        float v = red[0][t] + red[1][t] + red[2][t] + red[3][t];
        atomicAdd((float*)&acc[A_SUMS + b * 12 + t], v);
    }
}

__global__ void k_loss(const int* __restrict__ acc, float* __restrict__ out) {
    if (threadIdx.x == 0 && blockIdx.x == 0) {
        const float* sums = (const float*)&acc[A_SUMS];
        float total = 0.0f;
        for (int b = 0; b < NB; b++) {
            int n = acc[A_ROOTCNT + b];
            int K = (n > 5) ? 5 : n;
            float s = 0.0f;
            for (int r = 0; r < 4; r++) {
                if (r < K) {
                    float A = sums[b * 12 + r];        // sum xs by voronoi seg
                    float M = sums[b * 12 + 4 + r];    // sum xs over comp r+1
                    float C = sums[b * 12 + 8 + r];    // count comp r+1
                    float inter = (float)(r + 1) * M;
                    float sy = (float)(r + 1) * C;
                    s += 2.0f * inter / (A + sy);
                }
            }
            float Kf = (float)(K > 0 ? K : 1);
            total += (K == 0) ? 1.0f : (1.0f - s / Kf);
        }
        out[0] = total / (float)NB;
    }
}

extern "C" void kernel_launch(void* const* d_in, const int* in_sizes, int n_in,
                              void* d_out, int out_size, void* d_ws, size_t ws_size,
                              hipStream_t stream) {
    const float* x = (const float*)d_in[0];
    const int*   y = (const int*)d_in[1];
    float* out = (float*)d_out;

    char* ws = (char*)d_ws;
    int*   acc = (int*)ws;
    int*   lab = (int*)(ws + 1024);
    float* kA  = (float*)(ws + 1024 + (size_t)NB * DHW * 4);
    float* kB  = (float*)((char*)kA + (size_t)NB * DHW * 4);

    dim3 blk(256);
    dim3 g1((NB * DHW) / 256);   // 6912, exact
    dim3 g2(NB * 1152);          // 2304 tiles per pass
    dim3 gl(NB * 1728);          // 3456 CCL tiles

    k_local<<<gl, blk, 0, stream>>>(y, lab, acc);
    k_bmerge<<<g1, blk, 0, stream>>>(y, lab);
    k_roots<<<g1, blk, 0, stream>>>(lab, acc);
    k_pedtD<<<g2, blk, 0, stream>>>(lab, acc, kA);
    k_pedtH<<<g2, blk, 0, stream>>>(kA, kB);
    k_pedtW_acc<<<g2, blk, 0, stream>>>(kB, x, lab, acc);
    k_loss<<<1, 64, 0, stream>>>(acc, out);
}